// Round 1
// baseline (186.107 us; speedup 1.0000x reference)
//
#include <hip/hip_runtime.h>
#include <hip/hip_bf16.h>

typedef unsigned short u16;
typedef __attribute__((ext_vector_type(8))) short bf16x8;
typedef __attribute__((ext_vector_type(4))) float f32x4;

#define B_ 16
#define CIN 256
#define COUT 256
#define NPIX 4096
#define E_ 8

__device__ __forceinline__ u16 f2bf(float f){
    union { float f; unsigned int u; } v; v.f = f;
    return (u16)((v.u + 0x7FFFu + ((v.u >> 16) & 1u)) >> 16);
}

// -------- 1) global average pool: pooled[b][c] --------
__global__ void k_pool(const float* __restrict__ x, float* __restrict__ pooled){
    int bc = blockIdx.x;
    const float4* s4 = (const float4*)(x + (size_t)bc * NPIX);
    int t = threadIdx.x;
    float s = 0.f;
    #pragma unroll
    for (int i = 0; i < 4; ++i){
        float4 v = s4[t + i*256];
        s += v.x + v.y + v.z + v.w;
    }
    #pragma unroll
    for (int off = 32; off; off >>= 1) s += __shfl_down(s, off, 64);
    __shared__ float ls[4];
    if ((t & 63) == 0) ls[t >> 6] = s;
    __syncthreads();
    if (t == 0) pooled[bc] = (ls[0]+ls[1]+ls[2]+ls[3]) * (1.0f/(float)NPIX);
}

// -------- 2) routing + aggregated bias --------
__global__ void k_route(const float* __restrict__ pooled, const float* __restrict__ rw,
                        const float* __restrict__ rb, const float* __restrict__ bias,
                        float* __restrict__ routing, float* __restrict__ aggb)
{
    __shared__ float r_s[B_*E_];
    int t = threadIdx.x;
    if (t < B_*E_){
        int b = t >> 3, e = t & 7;
        float s = rb[e];
        const float* pp = pooled + b*CIN;
        const float* wp = rw + e*CIN;
        for (int i = 0; i < CIN; ++i) s += pp[i]*wp[i];
        float r = 1.0f/(1.0f + __expf(-s));
        routing[t] = r;
        r_s[t] = r;
    }
    __syncthreads();
    for (int idx = t; idx < B_*COUT; idx += 256){
        int b = idx >> 8, o = idx & 255;
        float s = 0.f;
        #pragma unroll
        for (int e = 0; e < E_; ++e) s += r_s[b*E_+e]*bias[e*COUT+o];
        aggb[idx] = s;
    }
}

// -------- 3) aggregated weights, bf16, layout [b][o][tap][cin] --------
__global__ void k_aggw(const float* __restrict__ weight, const float* __restrict__ routing,
                       u16* __restrict__ aggw)
{
    int o = blockIdx.x, i = threadIdx.x;
    __shared__ float r_s[B_*E_];
    if (i < B_*E_) r_s[i] = routing[i];
    __syncthreads();
    float w[E_][9];
    #pragma unroll
    for (int e = 0; e < E_; ++e){
        const float* wp = weight + (((size_t)(e*COUT + o))*CIN + i)*9;
        #pragma unroll
        for (int tp = 0; tp < 9; ++tp) w[e][tp] = wp[tp];
    }
    for (int b = 0; b < B_; ++b){
        float acc[9];
        #pragma unroll
        for (int tp = 0; tp < 9; ++tp) acc[tp] = 0.f;
        #pragma unroll
        for (int e = 0; e < E_; ++e){
            float r = r_s[b*E_+e];
            #pragma unroll
            for (int tp = 0; tp < 9; ++tp) acc[tp] += r*w[e][tp];
        }
        #pragma unroll
        for (int tp = 0; tp < 9; ++tp)
            aggw[(((size_t)(b*COUT + o))*9 + tp)*CIN + i] = f2bf(acc[tp]);
    }
}

// -------- 4) transpose+convert: x_t[b][p][cin] bf16 --------
__global__ void k_xt(const float* __restrict__ x, u16* __restrict__ xt){
    __shared__ float tile[64][65];
    int bid = blockIdx.x;
    int b = bid >> 8, ct = (bid >> 6) & 3, pt = bid & 63;
    int c0 = ct*64, p0 = pt*64, t = threadIdx.x;
    #pragma unroll
    for (int iter = 0; iter < 4; ++iter){
        int idx = t*4 + iter*1024;
        int r = idx >> 6, c4 = idx & 63;
        float4 v = *(const float4*)(x + ((size_t)(b*CIN + c0 + r))*NPIX + p0 + c4);
        tile[r][c4+0] = v.x; tile[r][c4+1] = v.y; tile[r][c4+2] = v.z; tile[r][c4+3] = v.w;
    }
    __syncthreads();
    #pragma unroll
    for (int iter = 0; iter < 4; ++iter){
        int idx = t*4 + iter*1024;
        int pr = idx >> 6, cc = idx & 63;
        ushort4 u;
        u.x = f2bf(tile[cc+0][pr]);
        u.y = f2bf(tile[cc+1][pr]);
        u.z = f2bf(tile[cc+2][pr]);
        u.w = f2bf(tile[cc+3][pr]);
        *(ushort4*)(xt + ((size_t)(b*NPIX + p0 + pr))*CIN + c0 + cc) = u;
    }
}

// -------- 5) implicit-GEMM conv, 128x128 tile, mfma 16x16x32 bf16 --------
__global__ __launch_bounds__(256) void k_conv(
    const u16* __restrict__ aggw, const u16* __restrict__ xt,
    const float* __restrict__ aggb, float* __restrict__ out)
{
    __shared__ u16 As[128*40];   // [row m][kk], stride 40 (80B) to spread banks
    __shared__ u16 Bs[128*40];   // [row p][kk]

    int bid = blockIdx.x;
    int b  = bid >> 6;
    int mt = (bid >> 5) & 1;
    int pt = bid & 31;
    int m0 = mt << 7;
    int p0 = pt << 7;

    int t = threadIdx.x;
    int lane = t & 63;
    int w = t >> 6;
    int wm = (w >> 1) << 6;      // wave sub-tile row base: 0 / 64
    int wn = (w & 1) << 6;       // wave sub-tile col base: 0 / 64
    int l16 = lane & 15;
    int g8 = (lane >> 4) << 3;   // k offset within fragment: 0,8,16,24

    int rowA = t >> 2;           // 0..63 (staging row within half-tile)
    int kk0  = (t & 3) << 3;     // 0,8,16,24 (staging k chunk)

    int lw0 = rowA*40 + kk0;
    int lw1 = (rowA+64)*40 + kk0;

    const u16* aggw_b0 = aggw + ((size_t)(b*COUT + m0 + rowA))      * (9*CIN);
    const u16* aggw_b1 = aggw + ((size_t)(b*COUT + m0 + rowA + 64)) * (9*CIN);
    const u16* xt_b = xt + ((size_t)b * NPIX) * CIN;

    int y0 = pt << 1;            // output image rows of this tile: y0, y0+1
    int xc = rowA;               // output image column of staged pixel

    f32x4 acc[4][4];
    #pragma unroll
    for (int i = 0; i < 4; ++i)
        #pragma unroll
        for (int j = 0; j < 4; ++j){
            f32x4 z = {0.f, 0.f, 0.f, 0.f};
            acc[i][j] = z;
        }

    for (int tap = 0; tap < 9; ++tap){
        int kh = tap / 3, kw = tap - kh*3;
        int sx  = xc + kw - 1;
        int sy0 = y0 + kh - 1;
        int sy1 = sy0 + 1;
        bool vx = ((unsigned)sx  < 64u);
        bool v0 = vx && ((unsigned)sy0 < 64u);
        bool v1 = vx && ((unsigned)sy1 < 64u);
        const u16* bsrc0 = xt_b + ((long long)(sy0*64 + sx))*CIN + kk0;
        const u16* bsrc1 = xt_b + ((long long)(sy1*64 + sx))*CIN + kk0;
        const u16* asrc0 = aggw_b0 + tap*CIN + kk0;
        const u16* asrc1 = aggw_b1 + tap*CIN + kk0;

        for (int c0 = 0; c0 < CIN; c0 += 32){
            uint4 ra0 = *(const uint4*)(asrc0 + c0);
            uint4 ra1 = *(const uint4*)(asrc1 + c0);
            uint4 rb0 = {0u,0u,0u,0u}, rb1 = {0u,0u,0u,0u};
            if (v0) rb0 = *(const uint4*)(bsrc0 + c0);
            if (v1) rb1 = *(const uint4*)(bsrc1 + c0);

            __syncthreads();                     // previous iter's reads done
            *(uint4*)(As + lw0) = ra0;
            *(uint4*)(As + lw1) = ra1;
            *(uint4*)(Bs + lw0) = rb0;
            *(uint4*)(Bs + lw1) = rb1;
            __syncthreads();                     // tiles ready

            bf16x8 af[4], bfv[4];
            #pragma unroll
            for (int mf = 0; mf < 4; ++mf)
                af[mf] = *(const bf16x8*)(As + (wm + mf*16 + l16)*40 + g8);
            #pragma unroll
            for (int nf = 0; nf < 4; ++nf)
                bfv[nf] = *(const bf16x8*)(Bs + (wn + nf*16 + l16)*40 + g8);
            #pragma unroll
            for (int mf = 0; mf < 4; ++mf)
                #pragma unroll
                for (int nf = 0; nf < 4; ++nf)
                    acc[mf][nf] = __builtin_amdgcn_mfma_f32_16x16x32_bf16(
                        af[mf], bfv[nf], acc[mf][nf], 0, 0, 0);
        }
    }

    // epilogue: += aggregated bias, write fp32
    const float* ab = aggb + b*COUT + m0;
    float* outp = out + ((size_t)(b*COUT + m0))*NPIX + p0;
    #pragma unroll
    for (int mf = 0; mf < 4; ++mf){
        #pragma unroll
        for (int v = 0; v < 4; ++v){
            int r = wm + mf*16 + (g8 >> 1) + v;   // (g8>>1) = 4*(lane>>4)
            float bias_r = ab[r];
            float* orow = outp + (size_t)r*NPIX;
            #pragma unroll
            for (int nf = 0; nf < 4; ++nf)
                orow[wn + nf*16 + l16] = acc[mf][nf][v] + bias_r;
        }
    }
}

extern "C" void kernel_launch(void* const* d_in, const int* in_sizes, int n_in,
                              void* d_out, int out_size, void* d_ws, size_t ws_size,
                              hipStream_t stream)
{
    const float* x      = (const float*)d_in[0];
    const float* weight = (const float*)d_in[1];
    const float* bias   = (const float*)d_in[2];
    const float* rw     = (const float*)d_in[3];
    const float* rb     = (const float*)d_in[4];
    float* out = (float*)d_out;

    char* ws = (char*)d_ws;
    u16*   aggw    = (u16*)(ws);                         // 18,874,368 B
    u16*   xt      = (u16*)(ws + 18874368);              // 33,554,432 B
    float* pooled  = (float*)(ws + 52428800);            // 16 KB
    float* routing = (float*)(ws + 52428800 + 16384);    // 512 B
    float* aggb    = (float*)(ws + 52428800 + 16384 + 512); // 16 KB

    k_pool <<<B_*CIN, 256, 0, stream>>>(x, pooled);
    k_route<<<1,      256, 0, stream>>>(pooled, rw, rb, bias, routing, aggb);
    k_aggw <<<COUT,   256, 0, stream>>>(weight, routing, aggw);
    k_xt   <<<4096,   256, 0, stream>>>(x, xt);
    k_conv <<<1024,   256, 0, stream>>>(aggw, xt, aggb, out);
}